// Round 18
// baseline (177.391 us; speedup 1.0000x reference)
//
#include <hip/hip_runtime.h>

// Problem constants: N=100000 nodes, E=1.6M edges, D=128, H=O=64.
constexpr int FD = 64;    // feature dim of both layers
constexpr int P  = 8;     // level-1 dst buckets (~XCDs)
constexpr int WN = 125;   // nodes per window (level-2)
constexpr int SRC_BITS = 17;                 // src id fits 17 bits (N <= 131072)
constexpr int SRC_MASK = (1 << SRC_BITS) - 1;
constexpr int G1S = 16;   // gcur1 stride (one counter per 64B line)

typedef __attribute__((ext_vector_type(8))) short bf16x8;   // 8 bf16 (4 VGPRs)
typedef __attribute__((ext_vector_type(4))) float f32x4;    // MFMA accum / NT store

__device__ __forceinline__ int part_of(int d, unsigned long long M) {
    return (int)(((unsigned long long)(unsigned)d * M) >> 32);  // == d / npp
}
// f32 -> bf16 round-to-nearest-even
__device__ __forceinline__ unsigned short bf16r(float x) {
    unsigned u = __float_as_uint(x);
    return (unsigned short)((u + 0x7FFFu + ((u >> 16) & 1u)) >> 16);
}
// pack two f32 -> two bf16 (RNE) in one uint
__device__ __forceinline__ unsigned bf16pack(float a, float b) {
    unsigned ua = __float_as_uint(a), ub = __float_as_uint(b);
    ua = (ua + 0x7FFFu + ((ua >> 16) & 1u)) >> 16;
    ub = (ub + 0x7FFFu + ((ub >> 16) & 1u)) >> 16;
    return ua | (ub << 16);
}
// accumulate 8 bf16 (uint4) into two float4
__device__ __forceinline__ void addu4(float4& A, float4& B, uint4 u) {
    A.x += __uint_as_float(u.x << 16); A.y += __uint_as_float(u.x & 0xFFFF0000u);
    A.z += __uint_as_float(u.y << 16); A.w += __uint_as_float(u.y & 0xFFFF0000u);
    B.x += __uint_as_float(u.z << 16); B.y += __uint_as_float(u.z & 0xFFFF0000u);
    B.z += __uint_as_float(u.w << 16); B.w += __uint_as_float(u.w & 0xFFFF0000u);
}

// ---------------- prelude: cursors + transposed bf16 weights -----------------
__global__ void k_pre(int* __restrict__ gcur1, int cap1,
                      int* __restrict__ gcur2, int cap2, int NW,
                      const float* __restrict__ W1, const float* __restrict__ W2,
                      unsigned short* __restrict__ Wt1, unsigned short* __restrict__ Wt2) {
    int i = blockIdx.x * 256 + threadIdx.x;
    if (i < P)  gcur1[i * G1S] = i * cap1;
    if (i < NW) gcur2[i] = i * cap2;
    if (i < 64 * 128) {
        int c = i >> 7, k = i & 127;
        Wt1[i] = bf16r(W1[(size_t)k * 64 + c]);
    }
    int j = i - 64 * 128;
    if (j >= 0 && j < 64 * 64) {
        int c = j >> 6, k = j & 63;
        Wt2[j] = bf16r(W2[(size_t)k * 64 + c]);
    }
}

// ---------------- level 1: 8-way split, 3-ballot multisplit, single pass -----
__global__ __launch_bounds__(256) void k_part8(const int* __restrict__ src,
                                               const int* __restrict__ dst, int E,
                                               unsigned long long M, int npp,
                                               int* __restrict__ gcur1, int cap1,
                                               int* __restrict__ p1) {
    constexpr int CH = 1024;
    __shared__ int hh[P], bbase[P], lcur[P];
    if (threadIdx.x < P) hh[threadIdx.x] = 0;
    __syncthreads();
    const int e0  = blockIdx.x * CH;
    const int rem = min(CH, E - e0);
    const int lane = threadIdx.x & 63;
    const unsigned long long lmlt = (lane == 63) ? ~0ull >> 1 : (1ull << lane) - 1;

    int dv[4], sv[4], bv[4], ldr[4], rnk[4], cnt[4];
    bool val[4];
#pragma unroll
    for (int j = 0; j < 4; ++j) {
        int i = j * 256 + threadIdx.x;
        val[j] = i < rem;
        int e = e0 + (val[j] ? i : 0);
        dv[j] = __builtin_nontemporal_load(&dst[e]);
        sv[j] = __builtin_nontemporal_load(&src[e]);
        bv[j] = part_of(dv[j], M);
    }
#pragma unroll
    for (int j = 0; j < 4; ++j) {
        unsigned long long m0 = __ballot(val[j] && (bv[j] & 1));
        unsigned long long m1 = __ballot(val[j] && (bv[j] & 2));
        unsigned long long m2 = __ballot(val[j] && (bv[j] & 4));
        unsigned long long mv = __ballot(val[j]);
        unsigned long long t = ((bv[j] & 1) ? m0 : ~m0)
                             & ((bv[j] & 2) ? m1 : ~m1)
                             & ((bv[j] & 4) ? m2 : ~m2) & mv;
        ldr[j] = __ffsll((unsigned long long)t) - 1;
        rnk[j] = __popcll(t & lmlt);
        cnt[j] = __popcll(t);
        if (val[j] && lane == ldr[j]) atomicAdd(&hh[bv[j]], cnt[j]);
    }
    __syncthreads();
    if (threadIdx.x < P) {
        bbase[threadIdx.x] = atomicAdd(&gcur1[threadIdx.x * G1S], hh[threadIdx.x]);
        lcur[threadIdx.x] = 0;
    }
    __syncthreads();
#pragma unroll
    for (int j = 0; j < 4; ++j) {
        int wb = 0;
        if (val[j] && lane == ldr[j]) wb = atomicAdd(&lcur[bv[j]], cnt[j]);
        wb = __shfl(wb, ldr[j] < 0 ? 0 : ldr[j], 64);   // group-leader broadcast
        if (val[j]) {
            int pos = bbase[bv[j]] + wb + rnk[j];
            if (pos < (bv[j] + 1) * cap1)
                p1[pos] = ((dv[j] - bv[j] * npp) << SRC_BITS) | sv[j];
        }
    }
}

// ---------------- level 2: split bucket into 125-node windows ----------------
__global__ __launch_bounds__(256) void k_partwin(const int* __restrict__ p1,
                                                 const int* __restrict__ gcur1, int cap1,
                                                 int npp, unsigned long long M2,
                                                 int* __restrict__ gcur2, int cap2,
                                                 int* __restrict__ p2) {
    constexpr int CH = 1024;
    constexpr int MAXW = 128;
    __shared__ int hh[MAXW], wbase[MAXW], lcur[MAXW];
    const int p   = blockIdx.x & (P - 1);
    const int j   = blockIdx.x >> 3;
    const int wlo = (p * npp) / WN;
    const int whi = ((p + 1) * npp - 1) / WN;
    const int nw  = whi - wlo + 1;             // <= 101
    const int lo = p * cap1 + j * CH;
    const int hi = min(lo + CH, gcur1[p * G1S]);
    if (lo >= hi) return;                       // block-uniform
    for (int t = threadIdx.x; t < nw; t += 256) hh[t] = 0;
    __syncthreads();
    int pk[4], wv[4];
    bool val[4];
#pragma unroll
    for (int q = 0; q < 4; ++q) {
        int e = lo + q * 256 + threadIdx.x;
        val[q] = e < hi;
        pk[q] = val[q] ? __builtin_nontemporal_load(&p1[e]) : 0;
        int d = p * npp + (pk[q] >> SRC_BITS);
        wv[q] = (int)(((unsigned long long)(unsigned)d * M2) >> 32);   // d/WN
        if (val[q]) atomicAdd(&hh[wv[q] - wlo], 1);
    }
    __syncthreads();
    for (int t = threadIdx.x; t < nw; t += 256) {
        wbase[t] = hh[t] ? atomicAdd(&gcur2[wlo + t], hh[t]) : 0;
        lcur[t] = 0;
    }
    __syncthreads();
#pragma unroll
    for (int q = 0; q < 4; ++q) {
        if (val[q]) {
            int w  = wv[q];
            int hw = w - wlo;
            int d  = p * npp + (pk[q] >> SRC_BITS);
            int pos = wbase[hw] + atomicAdd(&lcur[hw], 1);
            if (pos < (w + 1) * cap2)
                p2[pos] = ((d - w * WN) << SRC_BITS) | (pk[q] & SRC_MASK);
        }
    }
}

// ---------------- level 3: counting sort per window + degree-ranked slots ----
__global__ __launch_bounds__(256) void k_sortwin(int* __restrict__ p2,
                                                 const int* __restrict__ gcur2, int cap2,
                                                 int* __restrict__ rowinfo2,
                                                 int* __restrict__ nid,
                                                 float* __restrict__ dinv, int N) {
    __shared__ int hist[WN], beg[WN], cur[WN], dh[64], dbs[64];
    const int w  = blockIdx.x;
    const int lo = w * cap2;
    const int hi = min(gcur2[w], lo + cap2);
    const int cnt = hi - lo;
    for (int t = threadIdx.x; t < WN; t += 256) hist[t] = 0;
    if (threadIdx.x < 64) dh[threadIdx.x] = 0;
    __syncthreads();
    int pk[10];                      // cap2 <= 2560 = 10*256
#pragma unroll
    for (int j = 0; j < 10; ++j) {
        int i = j * 256 + threadIdx.x;
        pk[j] = (i < cnt) ? p2[lo + i] : -1;
        if (pk[j] >= 0) atomicAdd(&hist[pk[j] >> SRC_BITS], 1);
    }
    __syncthreads();
    if (threadIdx.x < 64) {          // wave 0: exclusive scan of hist[0..124]
        int lane = threadIdx.x;
        int v0 = hist[lane];
        int x0 = v0;
#pragma unroll
        for (int o = 1; o < 64; o <<= 1) { int y = __shfl_up(x0, o, 64); if (lane >= o) x0 += y; }
        int tot0 = __shfl(x0, 63, 64);
        int v1 = (lane < WN - 64) ? hist[64 + lane] : 0;
        int x1 = v1;
#pragma unroll
        for (int o = 1; o < 64; o <<= 1) { int y = __shfl_up(x1, o, 64); if (lane >= o) x1 += y; }
        int b0 = x0 - v0;
        beg[lane] = b0; cur[lane] = b0;
        if (lane < WN - 64) {
            int b1 = tot0 + x1 - v1;
            beg[64 + lane] = b1; cur[64 + lane] = b1;
        }
    }
    // degree-bin count (intra-bin rank from atomicAdd return)
    int mybin = -1, myir = 0;
    if (threadIdx.x < WN) {
        mybin = min(hist[threadIdx.x], 63);
        myir  = atomicAdd(&dh[mybin], 1);
    }
    __syncthreads();
#pragma unroll
    for (int j = 0; j < 10; ++j) {
        if (pk[j] >= 0) {
            int ld  = pk[j] >> SRC_BITS;
            int pos = atomicAdd(&cur[ld], 1);
            p2[lo + pos] = pk[j] & SRC_MASK;   // sorted src id
        }
    }
    if (threadIdx.x < 64) {          // wave 0: exclusive scan of 64 degree bins
        int lane = threadIdx.x;
        int v = dh[lane], x = v;
#pragma unroll
        for (int o = 1; o < 64; o <<= 1) { int y = __shfl_up(x, o, 64); if (lane >= o) x += y; }
        dbs[lane] = x - v;
    }
    __syncthreads();
    if (threadIdx.x < WN) {
        int t = threadIdx.x;
        int node = w * WN + t;
        if (node < N) {
            int rank = dbs[mybin] + myir;
            int slot = w * WN + rank;
            rowinfo2[slot] = beg[t] | (hist[t] << 16);
            nid[slot] = node;
            dinv[node] = rsqrtf((float)(hist[t] + 1));   // +1 self-loop
        }
    }
}

// ---------------- MFMA GEMM (layer 1): Ab1 = bf16(dinv .* (emb @ W1)) --------
__global__ __launch_bounds__(256) void k_gemm1(const float* __restrict__ Xf,
                                               const uint4* __restrict__ Wt,
                                               const float* __restrict__ dinv,
                                               unsigned short* __restrict__ Yb,
                                               int n) {
    constexpr int K = 128, NT = 4, RQ4 = 16;
    const int wv = threadIdx.x >> 6;          // wave 0..3
    const int l  = threadIdx.x & 63;
    const int r  = l & 15, hi = l >> 4;
    const int row = blockIdx.x * 64 + wv * 16 + r;   // A-frag row
    union U { uint4 u; bf16x8 v; };
    f32x4 acc[4] = {};

#pragma unroll
    for (int t = 0; t < NT; ++t) {
        U a;
        float4 f0 = make_float4(0.f, 0.f, 0.f, 0.f);
        float4 f1 = make_float4(0.f, 0.f, 0.f, 0.f);
        if (row < n) {
            f0 = *(const float4*)&Xf[(size_t)row * K + t * 32 + hi * 8];
            f1 = *(const float4*)&Xf[(size_t)row * K + t * 32 + hi * 8 + 4];
        }
        a.u.x = bf16pack(f0.x, f0.y);
        a.u.y = bf16pack(f0.z, f0.w);
        a.u.z = bf16pack(f1.x, f1.y);
        a.u.w = bf16pack(f1.z, f1.w);
#pragma unroll
        for (int cb = 0; cb < 4; ++cb) {
            U b;
            b.u = Wt[(size_t)(cb * 16 + r) * RQ4 + t * 4 + hi];
            acc[cb] = __builtin_amdgcn_mfma_f32_16x16x32_bf16(a.v, b.v, acc[cb], 0, 0, 0);
        }
    }
    const int orow0 = blockIdx.x * 64 + wv * 16 + hi * 4;
#pragma unroll
    for (int j = 0; j < 4; ++j) {
        int orow = orow0 + j;
        if (orow < n) {
            float sc = dinv[orow];
#pragma unroll
            for (int cb = 0; cb < 4; ++cb)
                Yb[(size_t)orow * 64 + cb * 16 + r] = bf16r(acc[cb][j] * sc);
        }
    }
}

// ---------------- fused layer-1 agg + layer-2 GEMM (8 lanes/node) ------------
__global__ __launch_bounds__(256) void k_agg_fuse(const uint4* __restrict__ Xr,
                                                  const int* __restrict__ col,
                                                  const int* __restrict__ rowinfo2,
                                                  const int* __restrict__ nid,
                                                  int cap2, unsigned long long M2,
                                                  const float* __restrict__ dinv,
                                                  const float* __restrict__ bias,
                                                  const uint4* __restrict__ Wt2,
                                                  unsigned short* __restrict__ Yb,
                                                  int n) {
    __shared__ __align__(16) unsigned hrow[32][36];   // 32 rows x 64 bf16, pad->144B
    __shared__ int nidB[32];
    {
        int slot = blockIdx.x * 32 + (threadIdx.x >> 3);
        int lane = threadIdx.x & 7;
        int sb   = threadIdx.x >> 3;
        float4 h0 = {0,0,0,0}, h1 = {0,0,0,0};
        int node = -1;
        if (slot < n) {
            int info = rowinfo2[slot];
            node     = nid[slot];
            int w    = (int)(((unsigned long long)(unsigned)slot * M2) >> 32);  // slot/WN
            int beg  = w * cap2 + (info & 0xFFFF);
            int end  = beg + (info >> 16);
            uint4 svu = Xr[(size_t)node * 8 + lane];
            float4 p0 = {0,0,0,0}, p1 = {0,0,0,0}, q0 = {0,0,0,0}, q1 = {0,0,0,0};
            int e = beg;
            for (; e + 8 <= end; e += 8) {
                int s0 = __builtin_nontemporal_load(&col[e + 0]);
                int s1 = __builtin_nontemporal_load(&col[e + 1]);
                int s2 = __builtin_nontemporal_load(&col[e + 2]);
                int s3 = __builtin_nontemporal_load(&col[e + 3]);
                int s4 = __builtin_nontemporal_load(&col[e + 4]);
                int s5 = __builtin_nontemporal_load(&col[e + 5]);
                int s6 = __builtin_nontemporal_load(&col[e + 6]);
                int s7 = __builtin_nontemporal_load(&col[e + 7]);
                uint4 u0 = Xr[(size_t)s0 * 8 + lane];
                uint4 u1 = Xr[(size_t)s1 * 8 + lane];
                uint4 u2 = Xr[(size_t)s2 * 8 + lane];
                uint4 u3 = Xr[(size_t)s3 * 8 + lane];
                uint4 u4 = Xr[(size_t)s4 * 8 + lane];
                uint4 u5 = Xr[(size_t)s5 * 8 + lane];
                uint4 u6 = Xr[(size_t)s6 * 8 + lane];
                uint4 u7 = Xr[(size_t)s7 * 8 + lane];
                addu4(p0, p1, u0); addu4(q0, q1, u1);
                addu4(p0, p1, u2); addu4(q0, q1, u3);
                addu4(p0, p1, u4); addu4(q0, q1, u5);
                addu4(p0, p1, u6); addu4(q0, q1, u7);
            }
            for (; e + 4 <= end; e += 4) {
                int s0 = col[e], s1 = col[e + 1], s2 = col[e + 2], s3 = col[e + 3];
                uint4 u0 = Xr[(size_t)s0 * 8 + lane];
                uint4 u1 = Xr[(size_t)s1 * 8 + lane];
                uint4 u2 = Xr[(size_t)s2 * 8 + lane];
                uint4 u3 = Xr[(size_t)s3 * 8 + lane];
                addu4(p0, p1, u0); addu4(q0, q1, u1);
                addu4(p0, p1, u2); addu4(q0, q1, u3);
            }
            for (; e < end; ++e)
                addu4(p0, p1, Xr[(size_t)col[e] * 8 + lane]);
            addu4(p0, p1, svu);
            float di = dinv[node];
            float4 b0 = ((const float4*)bias)[lane * 2];
            float4 b1 = ((const float4*)bias)[lane * 2 + 1];
            h0.x = fmaxf(fmaf(di, p0.x + q0.x, b0.x), 0.f);
            h0.y = fmaxf(fmaf(di, p0.y + q0.y, b0.y), 0.f);
            h0.z = fmaxf(fmaf(di, p0.z + q0.z, b0.z), 0.f);
            h0.w = fmaxf(fmaf(di, p0.w + q0.w, b0.w), 0.f);
            h1.x = fmaxf(fmaf(di, p1.x + q1.x, b1.x), 0.f);
            h1.y = fmaxf(fmaf(di, p1.y + q1.y, b1.y), 0.f);
            h1.z = fmaxf(fmaf(di, p1.z + q1.z, b1.z), 0.f);
            h1.w = fmaxf(fmaf(di, p1.w + q1.w, b1.w), 0.f);
        }
        hrow[sb][lane * 4 + 0] = bf16pack(h0.x, h0.y);
        hrow[sb][lane * 4 + 1] = bf16pack(h0.z, h0.w);
        hrow[sb][lane * 4 + 2] = bf16pack(h1.x, h1.y);
        hrow[sb][lane * 4 + 3] = bf16pack(h1.z, h1.w);
        if (lane == 0) nidB[sb] = node;
    }
    __syncthreads();
    // Phase 2: wave wv -> row-tile rt = wv>>1 (16 rows), col blocks cb0,cb0+1.
    {
        const int wv = threadIdx.x >> 6;
        const int l  = threadIdx.x & 63;
        const int r  = l & 15, hi = l >> 4;
        const int rt = wv >> 1, cb0 = (wv & 1) * 2;
        union U { uint4 u; bf16x8 v; };
        f32x4 acc0 = {}, acc1 = {};
#pragma unroll
        for (int t = 0; t < 2; ++t) {
            U a, b0, b1;
            a.u  = *(const uint4*)&hrow[rt * 16 + r][t * 16 + hi * 4];
            b0.u = Wt2[(size_t)((cb0 + 0) * 16 + r) * 8 + t * 4 + hi];
            b1.u = Wt2[(size_t)((cb0 + 1) * 16 + r) * 8 + t * 4 + hi];
            acc0 = __builtin_amdgcn_mfma_f32_16x16x32_bf16(a.v, b0.v, acc0, 0, 0, 0);
            acc1 = __builtin_amdgcn_mfma_f32_16x16x32_bf16(a.v, b1.v, acc1, 0, 0, 0);
        }
#pragma unroll
        for (int j = 0; j < 4; ++j) {
            int node = nidB[rt * 16 + hi * 4 + j];
            if (node >= 0) {
                float sc = dinv[node];
                Yb[(size_t)node * 64 + (cb0 + 0) * 16 + r] = bf16r(acc0[j] * sc);
                Yb[(size_t)node * 64 + (cb0 + 1) * 16 + r] = bf16r(acc1[j] * sc);
            }
        }
    }
}

// ---------------- final aggregation (f32 out, 8 lanes/node, NT stores) -------
__global__ __launch_bounds__(256) void k_agg_f32(const uint4* __restrict__ Xr,
                                                 const int* __restrict__ col,
                                                 const int* __restrict__ rowinfo2,
                                                 const int* __restrict__ nid,
                                                 int cap2, unsigned long long M2,
                                                 const float* __restrict__ dinv,
                                                 const float* __restrict__ bias,
                                                 float* __restrict__ out, int n) {
    int slot = blockIdx.x * 32 + (threadIdx.x >> 3);
    int lane = threadIdx.x & 7;
    if (slot >= n) return;
    int info = rowinfo2[slot];
    int node = nid[slot];
    int w    = (int)(((unsigned long long)(unsigned)slot * M2) >> 32);   // slot/WN
    int beg  = w * cap2 + (info & 0xFFFF);
    int end  = beg + (info >> 16);
    uint4 svu = Xr[(size_t)node * 8 + lane];
    float4 p0 = {0,0,0,0}, p1 = {0,0,0,0}, q0 = {0,0,0,0}, q1 = {0,0,0,0};
    int e = beg;
    for (; e + 8 <= end; e += 8) {
        int s0 = __builtin_nontemporal_load(&col[e + 0]);
        int s1 = __builtin_nontemporal_load(&col[e + 1]);
        int s2 = __builtin_nontemporal_load(&col[e + 2]);
        int s3 = __builtin_nontemporal_load(&col[e + 3]);
        int s4 = __builtin_nontemporal_load(&col[e + 4]);
        int s5 = __builtin_nontemporal_load(&col[e + 5]);
        int s6 = __builtin_nontemporal_load(&col[e + 6]);
        int s7 = __builtin_nontemporal_load(&col[e + 7]);
        uint4 u0 = Xr[(size_t)s0 * 8 + lane];
        uint4 u1 = Xr[(size_t)s1 * 8 + lane];
        uint4 u2 = Xr[(size_t)s2 * 8 + lane];
        uint4 u3 = Xr[(size_t)s3 * 8 + lane];
        uint4 u4 = Xr[(size_t)s4 * 8 + lane];
        uint4 u5 = Xr[(size_t)s5 * 8 + lane];
        uint4 u6 = Xr[(size_t)s6 * 8 + lane];
        uint4 u7 = Xr[(size_t)s7 * 8 + lane];
        addu4(p0, p1, u0); addu4(q0, q1, u1);
        addu4(p0, p1, u2); addu4(q0, q1, u3);
        addu4(p0, p1, u4); addu4(q0, q1, u5);
        addu4(p0, p1, u6); addu4(q0, q1, u7);
    }
    for (; e + 4 <= end; e += 4) {
        int s0 = col[e], s1 = col[e + 1], s2 = col[e + 2], s3 = col[e + 3];
        uint4 u0 = Xr[(size_t)s0 * 8 + lane];
        uint4 u1 = Xr[(size_t)s1 * 8 + lane];
        uint4 u2 = Xr[(size_t)s2 * 8 + lane];
        uint4 u3 = Xr[(size_t)s3 * 8 + lane];
        addu4(p0, p1, u0); addu4(q0, q1, u1);
        addu4(p0, p1, u2); addu4(q0, q1, u3);
    }
    for (; e < end; ++e)
        addu4(p0, p1, Xr[(size_t)col[e] * 8 + lane]);
    addu4(p0, p1, svu);
    float di = dinv[node];
    float4 b0 = ((const float4*)bias)[lane * 2];
    float4 b1 = ((const float4*)bias)[lane * 2 + 1];
    f32x4 o0, o1;
    o0[0] = fmaf(di, p0.x + q0.x, b0.x);
    o0[1] = fmaf(di, p0.y + q0.y, b0.y);
    o0[2] = fmaf(di, p0.z + q0.z, b0.z);
    o0[3] = fmaf(di, p0.w + q0.w, b0.w);
    o1[0] = fmaf(di, p1.x + q1.x, b1.x);
    o1[1] = fmaf(di, p1.y + q1.y, b1.y);
    o1[2] = fmaf(di, p1.z + q1.z, b1.z);
    o1[3] = fmaf(di, p1.w + q1.w, b1.w);
    f32x4* orow = (f32x4*)(out + (size_t)node * FD);
    __builtin_nontemporal_store(o0, &orow[lane * 2]);
    __builtin_nontemporal_store(o1, &orow[lane * 2 + 1]);
}

// ---------------- launch ----------------

extern "C" void kernel_launch(void* const* d_in, const int* in_sizes, int n_in,
                              void* d_out, int out_size, void* d_ws, size_t ws_size,
                              hipStream_t stream) {
    const float* emb = (const float*)d_in[0];
    const float* W1  = (const float*)d_in[1];
    const float* b1  = (const float*)d_in[2];
    const float* W2  = (const float*)d_in[3];
    const float* b2  = (const float*)d_in[4];
    const int*   src = (const int*)d_in[5];
    const int*   dst = (const int*)d_in[6];

    const int D = 128;
    const int N = in_sizes[0] / D;   // 100000
    const int E = in_sizes[5];       // 1.6M
    float* out = (float*)d_out;

    const int npp  = (N + P - 1) / P;          // 12500 (< 2^14 for packing)
    const int NW   = (N + WN - 1) / WN;        // 800 windows
    const int cap1 = E / P + 16384;
    int cap2 = E / NW + 560;                   // 2560 = 10 regs * 256 thr
    if (cap2 > 2560) cap2 = 2560;              // k_sortwin register budget

    const unsigned long long M  = ((1ull << 32) + npp - 1) / npp;  // /npp
    const unsigned long long M2 = ((1ull << 32) + WN - 1) / WN;    // /125 (exact, d<2^17)

    // workspace (4B units): Ab1 | Ab2 | p2 | rowinfo2 | nid | dinv | gcur1 | gcur2 | Wt
    unsigned* Ab1  = (unsigned*)d_ws;                   // N*32 u32 (64 bf16/row)
    unsigned* Ab2  = Ab1 + (size_t)N * 32;              // N*32 u32
    int*   p2      = (int*)(Ab2 + (size_t)N * 32);      // NW*cap2
    int*   rowinfo2= p2 + (size_t)NW * cap2;            // N
    int*   nid     = rowinfo2 + N;                      // N
    float* dinv    = (float*)(nid + N);                 // N
    int*   gcur1   = (int*)(dinv + N);                  // P*G1S
    int*   gcur2   = gcur1 + P * G1S;                   // NW
    unsigned short* Wt1 = (unsigned short*)(gcur2 + ((NW + 3) & ~3));  // 64*128 bf16
    unsigned short* Wt2 = Wt1 + 64 * 128;               // 64*64 bf16
    int*   p1      = (int*)Ab1;                         // P*cap1 (aliases Ab1)

    k_pre<<<48, 256, 0, stream>>>(gcur1, cap1, gcur2, cap2, NW, W1, W2, Wt1, Wt2);
    k_part8<<<(E + 1023) / 1024, 256, 0, stream>>>(src, dst, E, M, npp, gcur1, cap1, p1);
    int nb2 = (cap1 + 1023) / 1024;
    k_partwin<<<P * nb2, 256, 0, stream>>>(p1, gcur1, cap1, npp, M2, gcur2, cap2, p2);
    k_sortwin<<<NW, 256, 0, stream>>>(p2, gcur2, cap2, rowinfo2, nid, dinv, N);

    // layer 1 GEMM: Ab1 = bf16(dinv.*(emb @ W1))
    k_gemm1<<<(N + 63) / 64, 256, 0, stream>>>(emb, (const uint4*)Wt1, dinv, (unsigned short*)Ab1, N);
    // fused: h = relu(dinv.*(sum Ab1)+b1); Ab2 = bf16(dinv.*(h @ W2))
    k_agg_fuse<<<(N * 8 + 255) / 256, 256, 0, stream>>>((const uint4*)Ab1, p2, rowinfo2, nid,
                                                        cap2, M2, dinv, b1,
                                                        (const uint4*)Wt2, (unsigned short*)Ab2, N);
    // final: out = dinv.*(sum Ab2) + b2  (f32, nontemporal)
    k_agg_f32<<<(N * 8 + 255) / 256, 256, 0, stream>>>((const uint4*)Ab2, p2, rowinfo2, nid,
                                                       cap2, M2, dinv, b2, out, N);
}

// Round 19
// 171.206 us; speedup vs baseline: 1.0361x; 1.0361x over previous
//
#include <hip/hip_runtime.h>

// Problem constants: N=100000 nodes, E=1.6M edges, D=128, H=O=64.
constexpr int FD = 64;    // feature dim of both layers
constexpr int P  = 8;     // level-1 dst buckets (~XCDs)
constexpr int WN = 125;   // nodes per window (level-2)
constexpr int SRC_BITS = 17;                 // src id fits 17 bits (N <= 131072)
constexpr int SRC_MASK = (1 << SRC_BITS) - 1;
constexpr int G1S = 16;   // gcur1 stride (one counter per 64B line)

typedef __attribute__((ext_vector_type(8))) short bf16x8;   // 8 bf16 (4 VGPRs)
typedef __attribute__((ext_vector_type(4))) float f32x4;    // MFMA accum

__device__ __forceinline__ int part_of(int d, unsigned long long M) {
    return (int)(((unsigned long long)(unsigned)d * M) >> 32);  // == d / npp
}
// f32 -> bf16 round-to-nearest-even
__device__ __forceinline__ unsigned short bf16r(float x) {
    unsigned u = __float_as_uint(x);
    return (unsigned short)((u + 0x7FFFu + ((u >> 16) & 1u)) >> 16);
}
// pack two f32 -> two bf16 (RNE) in one uint
__device__ __forceinline__ unsigned bf16pack(float a, float b) {
    unsigned ua = __float_as_uint(a), ub = __float_as_uint(b);
    ua = (ua + 0x7FFFu + ((ua >> 16) & 1u)) >> 16;
    ub = (ub + 0x7FFFu + ((ub >> 16) & 1u)) >> 16;
    return ua | (ub << 16);
}
// accumulate 8 bf16 (uint4) into two float4
__device__ __forceinline__ void addu4(float4& A, float4& B, uint4 u) {
    A.x += __uint_as_float(u.x << 16); A.y += __uint_as_float(u.x & 0xFFFF0000u);
    A.z += __uint_as_float(u.y << 16); A.w += __uint_as_float(u.y & 0xFFFF0000u);
    B.x += __uint_as_float(u.z << 16); B.y += __uint_as_float(u.z & 0xFFFF0000u);
    B.z += __uint_as_float(u.w << 16); B.w += __uint_as_float(u.w & 0xFFFF0000u);
}

// ---------------- prelude: cursors + transposed bf16 weights -----------------
__global__ void k_pre(int* __restrict__ gcur1, int cap1,
                      int* __restrict__ gcur2, int cap2, int NW,
                      const float* __restrict__ W1, const float* __restrict__ W2,
                      unsigned short* __restrict__ Wt1, unsigned short* __restrict__ Wt2) {
    int i = blockIdx.x * 256 + threadIdx.x;
    if (i < P)  gcur1[i * G1S] = i * cap1;
    if (i < NW) gcur2[i] = i * cap2;
    if (i < 64 * 128) {
        int c = i >> 7, k = i & 127;
        Wt1[i] = bf16r(W1[(size_t)k * 64 + c]);
    }
    int j = i - 64 * 128;
    if (j >= 0 && j < 64 * 64) {
        int c = j >> 6, k = j & 63;
        Wt2[j] = bf16r(W2[(size_t)k * 64 + c]);
    }
}

// ---------------- level 1: 8-way split, 3-ballot multisplit, single pass -----
__global__ __launch_bounds__(256) void k_part8(const int* __restrict__ src,
                                               const int* __restrict__ dst, int E,
                                               unsigned long long M, int npp,
                                               int* __restrict__ gcur1, int cap1,
                                               int* __restrict__ p1) {
    constexpr int CH = 1024;
    __shared__ int hh[P], bbase[P], lcur[P];
    if (threadIdx.x < P) hh[threadIdx.x] = 0;
    __syncthreads();
    const int e0  = blockIdx.x * CH;
    const int rem = min(CH, E - e0);
    const int lane = threadIdx.x & 63;
    const unsigned long long lmlt = (lane == 63) ? ~0ull >> 1 : (1ull << lane) - 1;

    int dv[4], sv[4], bv[4], ldr[4], rnk[4], cnt[4];
    bool val[4];
#pragma unroll
    for (int j = 0; j < 4; ++j) {
        int i = j * 256 + threadIdx.x;
        val[j] = i < rem;
        int e = e0 + (val[j] ? i : 0);
        dv[j] = __builtin_nontemporal_load(&dst[e]);
        sv[j] = __builtin_nontemporal_load(&src[e]);
        bv[j] = part_of(dv[j], M);
    }
#pragma unroll
    for (int j = 0; j < 4; ++j) {
        unsigned long long m0 = __ballot(val[j] && (bv[j] & 1));
        unsigned long long m1 = __ballot(val[j] && (bv[j] & 2));
        unsigned long long m2 = __ballot(val[j] && (bv[j] & 4));
        unsigned long long mv = __ballot(val[j]);
        unsigned long long t = ((bv[j] & 1) ? m0 : ~m0)
                             & ((bv[j] & 2) ? m1 : ~m1)
                             & ((bv[j] & 4) ? m2 : ~m2) & mv;
        ldr[j] = __ffsll((unsigned long long)t) - 1;
        rnk[j] = __popcll(t & lmlt);
        cnt[j] = __popcll(t);
        if (val[j] && lane == ldr[j]) atomicAdd(&hh[bv[j]], cnt[j]);
    }
    __syncthreads();
    if (threadIdx.x < P) {
        bbase[threadIdx.x] = atomicAdd(&gcur1[threadIdx.x * G1S], hh[threadIdx.x]);
        lcur[threadIdx.x] = 0;
    }
    __syncthreads();
#pragma unroll
    for (int j = 0; j < 4; ++j) {
        int wb = 0;
        if (val[j] && lane == ldr[j]) wb = atomicAdd(&lcur[bv[j]], cnt[j]);
        wb = __shfl(wb, ldr[j] < 0 ? 0 : ldr[j], 64);   // group-leader broadcast
        if (val[j]) {
            int pos = bbase[bv[j]] + wb + rnk[j];
            if (pos < (bv[j] + 1) * cap1)
                p1[pos] = ((dv[j] - bv[j] * npp) << SRC_BITS) | sv[j];
        }
    }
}

// ---------------- level 2: split bucket into 125-node windows ----------------
__global__ __launch_bounds__(256) void k_partwin(const int* __restrict__ p1,
                                                 const int* __restrict__ gcur1, int cap1,
                                                 int npp, unsigned long long M2,
                                                 int* __restrict__ gcur2, int cap2,
                                                 int* __restrict__ p2) {
    constexpr int CH = 1024;
    constexpr int MAXW = 128;
    __shared__ int hh[MAXW], wbase[MAXW], lcur[MAXW];
    const int p   = blockIdx.x & (P - 1);
    const int j   = blockIdx.x >> 3;
    const int wlo = (p * npp) / WN;
    const int whi = ((p + 1) * npp - 1) / WN;
    const int nw  = whi - wlo + 1;             // <= 101
    const int lo = p * cap1 + j * CH;
    const int hi = min(lo + CH, gcur1[p * G1S]);
    if (lo >= hi) return;                       // block-uniform
    for (int t = threadIdx.x; t < nw; t += 256) hh[t] = 0;
    __syncthreads();
    int pk[4], wv[4];
    bool val[4];
#pragma unroll
    for (int q = 0; q < 4; ++q) {
        int e = lo + q * 256 + threadIdx.x;
        val[q] = e < hi;
        pk[q] = val[q] ? __builtin_nontemporal_load(&p1[e]) : 0;
        int d = p * npp + (pk[q] >> SRC_BITS);
        wv[q] = (int)(((unsigned long long)(unsigned)d * M2) >> 32);   // d/WN
        if (val[q]) atomicAdd(&hh[wv[q] - wlo], 1);
    }
    __syncthreads();
    for (int t = threadIdx.x; t < nw; t += 256) {
        wbase[t] = hh[t] ? atomicAdd(&gcur2[wlo + t], hh[t]) : 0;
        lcur[t] = 0;
    }
    __syncthreads();
#pragma unroll
    for (int q = 0; q < 4; ++q) {
        if (val[q]) {
            int w  = wv[q];
            int hw = w - wlo;
            int d  = p * npp + (pk[q] >> SRC_BITS);
            int pos = wbase[hw] + atomicAdd(&lcur[hw], 1);
            if (pos < (w + 1) * cap2)
                p2[pos] = ((d - w * WN) << SRC_BITS) | (pk[q] & SRC_MASK);
        }
    }
}

// ---------------- level 3: counting sort per window + degree-ranked slots ----
__global__ __launch_bounds__(256) void k_sortwin(int* __restrict__ p2,
                                                 const int* __restrict__ gcur2, int cap2,
                                                 int* __restrict__ rowinfo2,
                                                 int* __restrict__ nid,
                                                 float* __restrict__ dinv, int N) {
    __shared__ int hist[WN], beg[WN], cur[WN], dh[64], dbs[64];
    const int w  = blockIdx.x;
    const int lo = w * cap2;
    const int hi = min(gcur2[w], lo + cap2);
    const int cnt = hi - lo;
    for (int t = threadIdx.x; t < WN; t += 256) hist[t] = 0;
    if (threadIdx.x < 64) dh[threadIdx.x] = 0;
    __syncthreads();
    int pk[10];                      // cap2 <= 2560 = 10*256
#pragma unroll
    for (int j = 0; j < 10; ++j) {
        int i = j * 256 + threadIdx.x;
        pk[j] = (i < cnt) ? p2[lo + i] : -1;
        if (pk[j] >= 0) atomicAdd(&hist[pk[j] >> SRC_BITS], 1);
    }
    __syncthreads();
    if (threadIdx.x < 64) {          // wave 0: exclusive scan of hist[0..124]
        int lane = threadIdx.x;
        int v0 = hist[lane];
        int x0 = v0;
#pragma unroll
        for (int o = 1; o < 64; o <<= 1) { int y = __shfl_up(x0, o, 64); if (lane >= o) x0 += y; }
        int tot0 = __shfl(x0, 63, 64);
        int v1 = (lane < WN - 64) ? hist[64 + lane] : 0;
        int x1 = v1;
#pragma unroll
        for (int o = 1; o < 64; o <<= 1) { int y = __shfl_up(x1, o, 64); if (lane >= o) x1 += y; }
        int b0 = x0 - v0;
        beg[lane] = b0; cur[lane] = b0;
        if (lane < WN - 64) {
            int b1 = tot0 + x1 - v1;
            beg[64 + lane] = b1; cur[64 + lane] = b1;
        }
    }
    // degree-bin count (intra-bin rank from atomicAdd return)
    int mybin = -1, myir = 0;
    if (threadIdx.x < WN) {
        mybin = min(hist[threadIdx.x], 63);
        myir  = atomicAdd(&dh[mybin], 1);
    }
    __syncthreads();
#pragma unroll
    for (int j = 0; j < 10; ++j) {
        if (pk[j] >= 0) {
            int ld  = pk[j] >> SRC_BITS;
            int pos = atomicAdd(&cur[ld], 1);
            p2[lo + pos] = pk[j] & SRC_MASK;   // sorted src id
        }
    }
    if (threadIdx.x < 64) {          // wave 0: exclusive scan of 64 degree bins
        int lane = threadIdx.x;
        int v = dh[lane], x = v;
#pragma unroll
        for (int o = 1; o < 64; o <<= 1) { int y = __shfl_up(x, o, 64); if (lane >= o) x += y; }
        dbs[lane] = x - v;
    }
    __syncthreads();
    if (threadIdx.x < WN) {
        int t = threadIdx.x;
        int node = w * WN + t;
        if (node < N) {
            int rank = dbs[mybin] + myir;
            int slot = w * WN + rank;
            rowinfo2[slot] = beg[t] | (hist[t] << 16);
            nid[slot] = node;
            dinv[node] = rsqrtf((float)(hist[t] + 1));   // +1 self-loop
        }
    }
}

// ---------------- MFMA GEMM (layer 1): Ab1 = bf16(dinv .* (emb @ W1)) --------
__global__ __launch_bounds__(256) void k_gemm1(const float* __restrict__ Xf,
                                               const uint4* __restrict__ Wt,
                                               const float* __restrict__ dinv,
                                               unsigned short* __restrict__ Yb,
                                               int n) {
    constexpr int K = 128, NT = 4, RQ4 = 16;
    const int wv = threadIdx.x >> 6;          // wave 0..3
    const int l  = threadIdx.x & 63;
    const int r  = l & 15, hi = l >> 4;
    const int row = blockIdx.x * 64 + wv * 16 + r;   // A-frag row
    union U { uint4 u; bf16x8 v; };
    f32x4 acc[4] = {};

#pragma unroll
    for (int t = 0; t < NT; ++t) {
        U a;
        float4 f0 = make_float4(0.f, 0.f, 0.f, 0.f);
        float4 f1 = make_float4(0.f, 0.f, 0.f, 0.f);
        if (row < n) {
            f0 = *(const float4*)&Xf[(size_t)row * K + t * 32 + hi * 8];
            f1 = *(const float4*)&Xf[(size_t)row * K + t * 32 + hi * 8 + 4];
        }
        a.u.x = bf16pack(f0.x, f0.y);
        a.u.y = bf16pack(f0.z, f0.w);
        a.u.z = bf16pack(f1.x, f1.y);
        a.u.w = bf16pack(f1.z, f1.w);
#pragma unroll
        for (int cb = 0; cb < 4; ++cb) {
            U b;
            b.u = Wt[(size_t)(cb * 16 + r) * RQ4 + t * 4 + hi];
            acc[cb] = __builtin_amdgcn_mfma_f32_16x16x32_bf16(a.v, b.v, acc[cb], 0, 0, 0);
        }
    }
    const int orow0 = blockIdx.x * 64 + wv * 16 + hi * 4;
#pragma unroll
    for (int j = 0; j < 4; ++j) {
        int orow = orow0 + j;
        if (orow < n) {
            float sc = dinv[orow];
#pragma unroll
            for (int cb = 0; cb < 4; ++cb)
                Yb[(size_t)orow * 64 + cb * 16 + r] = bf16r(acc[cb][j] * sc);
        }
    }
}

// ---------------- fused layer-1 agg + layer-2 GEMM (8 lanes/node) ------------
// Block = 32 degree-ranked slots. Phase 1: h = relu(dinv*(sum+self)+b1) ->
// bf16 LDS rows. Phase 2: 4 waves, 8 16x16 MFMA tiles: Ab2 = bf16(dinv*(h@W2)).
__global__ __launch_bounds__(256) void k_agg_fuse(const uint4* __restrict__ Xr,
                                                  const int* __restrict__ col,
                                                  const int* __restrict__ rowinfo2,
                                                  const int* __restrict__ nid,
                                                  int cap2, unsigned long long M2,
                                                  const float* __restrict__ dinv,
                                                  const float* __restrict__ bias,
                                                  const uint4* __restrict__ Wt2,
                                                  unsigned short* __restrict__ Yb,
                                                  int n) {
    __shared__ __align__(16) unsigned hrow[32][36];   // 32 rows x 64 bf16, pad->144B
    __shared__ int nidB[32];
    {
        int slot = blockIdx.x * 32 + (threadIdx.x >> 3);
        int lane = threadIdx.x & 7;
        int sb   = threadIdx.x >> 3;
        float4 h0 = {0,0,0,0}, h1 = {0,0,0,0};
        int node = -1;
        if (slot < n) {
            int info = rowinfo2[slot];
            node     = nid[slot];
            int w    = (int)(((unsigned long long)(unsigned)slot * M2) >> 32);  // slot/WN
            int beg  = w * cap2 + (info & 0xFFFF);
            int end  = beg + (info >> 16);
            uint4 svu = Xr[(size_t)node * 8 + lane];
            float4 p0 = {0,0,0,0}, p1 = {0,0,0,0}, q0 = {0,0,0,0}, q1 = {0,0,0,0};
            int e = beg;
            for (; e + 4 <= end; e += 4) {
                int s0 = col[e], s1 = col[e + 1], s2 = col[e + 2], s3 = col[e + 3];
                uint4 u0 = Xr[(size_t)s0 * 8 + lane];
                uint4 u1 = Xr[(size_t)s1 * 8 + lane];
                uint4 u2 = Xr[(size_t)s2 * 8 + lane];
                uint4 u3 = Xr[(size_t)s3 * 8 + lane];
                addu4(p0, p1, u0); addu4(q0, q1, u1);
                addu4(p0, p1, u2); addu4(q0, q1, u3);
            }
            for (; e < end; ++e)
                addu4(p0, p1, Xr[(size_t)col[e] * 8 + lane]);
            addu4(p0, p1, svu);
            float di = dinv[node];
            float4 b0 = ((const float4*)bias)[lane * 2];
            float4 b1 = ((const float4*)bias)[lane * 2 + 1];
            h0.x = fmaxf(fmaf(di, p0.x + q0.x, b0.x), 0.f);
            h0.y = fmaxf(fmaf(di, p0.y + q0.y, b0.y), 0.f);
            h0.z = fmaxf(fmaf(di, p0.z + q0.z, b0.z), 0.f);
            h0.w = fmaxf(fmaf(di, p0.w + q0.w, b0.w), 0.f);
            h1.x = fmaxf(fmaf(di, p1.x + q1.x, b1.x), 0.f);
            h1.y = fmaxf(fmaf(di, p1.y + q1.y, b1.y), 0.f);
            h1.z = fmaxf(fmaf(di, p1.z + q1.z, b1.z), 0.f);
            h1.w = fmaxf(fmaf(di, p1.w + q1.w, b1.w), 0.f);
        }
        hrow[sb][lane * 4 + 0] = bf16pack(h0.x, h0.y);
        hrow[sb][lane * 4 + 1] = bf16pack(h0.z, h0.w);
        hrow[sb][lane * 4 + 2] = bf16pack(h1.x, h1.y);
        hrow[sb][lane * 4 + 3] = bf16pack(h1.z, h1.w);
        if (lane == 0) nidB[sb] = node;
    }
    __syncthreads();
    // Phase 2: wave wv -> row-tile rt = wv>>1 (16 rows), col blocks cb0,cb0+1.
    {
        const int wv = threadIdx.x >> 6;
        const int l  = threadIdx.x & 63;
        const int r  = l & 15, hi = l >> 4;
        const int rt = wv >> 1, cb0 = (wv & 1) * 2;
        union U { uint4 u; bf16x8 v; };
        f32x4 acc0 = {}, acc1 = {};
#pragma unroll
        for (int t = 0; t < 2; ++t) {
            U a, b0, b1;
            a.u  = *(const uint4*)&hrow[rt * 16 + r][t * 16 + hi * 4];
            b0.u = Wt2[(size_t)((cb0 + 0) * 16 + r) * 8 + t * 4 + hi];
            b1.u = Wt2[(size_t)((cb0 + 1) * 16 + r) * 8 + t * 4 + hi];
            acc0 = __builtin_amdgcn_mfma_f32_16x16x32_bf16(a.v, b0.v, acc0, 0, 0, 0);
            acc1 = __builtin_amdgcn_mfma_f32_16x16x32_bf16(a.v, b1.v, acc1, 0, 0, 0);
        }
#pragma unroll
        for (int j = 0; j < 4; ++j) {
            int node = nidB[rt * 16 + hi * 4 + j];
            if (node >= 0) {
                float sc = dinv[node];
                Yb[(size_t)node * 64 + (cb0 + 0) * 16 + r] = bf16r(acc0[j] * sc);
                Yb[(size_t)node * 64 + (cb0 + 1) * 16 + r] = bf16r(acc1[j] * sc);
            }
        }
    }
}

// ---------------- final aggregation (f32 out, 8 lanes/node) ------------------
__global__ __launch_bounds__(256) void k_agg_f32(const uint4* __restrict__ Xr,
                                                 const int* __restrict__ col,
                                                 const int* __restrict__ rowinfo2,
                                                 const int* __restrict__ nid,
                                                 int cap2, unsigned long long M2,
                                                 const float* __restrict__ dinv,
                                                 const float* __restrict__ bias,
                                                 float* __restrict__ out, int n) {
    int slot = blockIdx.x * 32 + (threadIdx.x >> 3);
    int lane = threadIdx.x & 7;
    if (slot >= n) return;
    int info = rowinfo2[slot];
    int node = nid[slot];
    int w    = (int)(((unsigned long long)(unsigned)slot * M2) >> 32);   // slot/WN
    int beg  = w * cap2 + (info & 0xFFFF);
    int end  = beg + (info >> 16);
    uint4 svu = Xr[(size_t)node * 8 + lane];
    float4 p0 = {0,0,0,0}, p1 = {0,0,0,0}, q0 = {0,0,0,0}, q1 = {0,0,0,0};
    int e = beg;
    for (; e + 4 <= end; e += 4) {
        int s0 = col[e], s1 = col[e + 1], s2 = col[e + 2], s3 = col[e + 3];
        uint4 u0 = Xr[(size_t)s0 * 8 + lane];
        uint4 u1 = Xr[(size_t)s1 * 8 + lane];
        uint4 u2 = Xr[(size_t)s2 * 8 + lane];
        uint4 u3 = Xr[(size_t)s3 * 8 + lane];
        addu4(p0, p1, u0); addu4(q0, q1, u1);
        addu4(p0, p1, u2); addu4(q0, q1, u3);
    }
    for (; e < end; ++e)
        addu4(p0, p1, Xr[(size_t)col[e] * 8 + lane]);
    addu4(p0, p1, svu);
    float di = dinv[node];
    float4 b0 = ((const float4*)bias)[lane * 2];
    float4 b1 = ((const float4*)bias)[lane * 2 + 1];
    float4 o0, o1;
    o0.x = fmaf(di, p0.x + q0.x, b0.x);
    o0.y = fmaf(di, p0.y + q0.y, b0.y);
    o0.z = fmaf(di, p0.z + q0.z, b0.z);
    o0.w = fmaf(di, p0.w + q0.w, b0.w);
    o1.x = fmaf(di, p1.x + q1.x, b1.x);
    o1.y = fmaf(di, p1.y + q1.y, b1.y);
    o1.z = fmaf(di, p1.z + q1.z, b1.z);
    o1.w = fmaf(di, p1.w + q1.w, b1.w);
    float4* orow = (float4*)(out + (size_t)node * FD);
    orow[lane * 2]     = o0;
    orow[lane * 2 + 1] = o1;
}

// ---------------- launch ----------------

extern "C" void kernel_launch(void* const* d_in, const int* in_sizes, int n_in,
                              void* d_out, int out_size, void* d_ws, size_t ws_size,
                              hipStream_t stream) {
    const float* emb = (const float*)d_in[0];
    const float* W1  = (const float*)d_in[1];
    const float* b1  = (const float*)d_in[2];
    const float* W2  = (const float*)d_in[3];
    const float* b2  = (const float*)d_in[4];
    const int*   src = (const int*)d_in[5];
    const int*   dst = (const int*)d_in[6];

    const int D = 128;
    const int N = in_sizes[0] / D;   // 100000
    const int E = in_sizes[5];       // 1.6M
    float* out = (float*)d_out;

    const int npp  = (N + P - 1) / P;          // 12500 (< 2^14 for packing)
    const int NW   = (N + WN - 1) / WN;        // 800 windows
    const int cap1 = E / P + 16384;
    int cap2 = E / NW + 560;                   // 2560 = 10 regs * 256 thr
    if (cap2 > 2560) cap2 = 2560;              // k_sortwin register budget

    const unsigned long long M  = ((1ull << 32) + npp - 1) / npp;  // /npp
    const unsigned long long M2 = ((1ull << 32) + WN - 1) / WN;    // /125 (exact, d<2^17)

    // workspace (4B units): Ab1 | Ab2 | p2 | rowinfo2 | nid | dinv | gcur1 | gcur2 | Wt
    // p1 aliases Ab1 (consumed by k_partwin before gemm1 writes Ab1).
    unsigned* Ab1  = (unsigned*)d_ws;                   // N*32 u32 (64 bf16/row)
    unsigned* Ab2  = Ab1 + (size_t)N * 32;              // N*32 u32
    int*   p2      = (int*)(Ab2 + (size_t)N * 32);      // NW*cap2
    int*   rowinfo2= p2 + (size_t)NW * cap2;            // N
    int*   nid     = rowinfo2 + N;                      // N
    float* dinv    = (float*)(nid + N);                 // N
    int*   gcur1   = (int*)(dinv + N);                  // P*G1S
    int*   gcur2   = gcur1 + P * G1S;                   // NW
    unsigned short* Wt1 = (unsigned short*)(gcur2 + ((NW + 3) & ~3));  // 64*128 bf16
    unsigned short* Wt2 = Wt1 + 64 * 128;               // 64*64 bf16
    int*   p1      = (int*)Ab1;                         // P*cap1 (aliases Ab1)

    k_pre<<<48, 256, 0, stream>>>(gcur1, cap1, gcur2, cap2, NW, W1, W2, Wt1, Wt2);
    k_part8<<<(E + 1023) / 1024, 256, 0, stream>>>(src, dst, E, M, npp, gcur1, cap1, p1);
    int nb2 = (cap1 + 1023) / 1024;
    k_partwin<<<P * nb2, 256, 0, stream>>>(p1, gcur1, cap1, npp, M2, gcur2, cap2, p2);
    k_sortwin<<<NW, 256, 0, stream>>>(p2, gcur2, cap2, rowinfo2, nid, dinv, N);

    // layer 1 GEMM: Ab1 = bf16(dinv.*(emb @ W1))
    k_gemm1<<<(N + 63) / 64, 256, 0, stream>>>(emb, (const uint4*)Wt1, dinv, (unsigned short*)Ab1, N);
    // fused: h = relu(dinv.*(sum Ab1)+b1); Ab2 = bf16(dinv.*(h @ W2))
    k_agg_fuse<<<(N * 8 + 255) / 256, 256, 0, stream>>>((const uint4*)Ab1, p2, rowinfo2, nid,
                                                        cap2, M2, dinv, b1,
                                                        (const uint4*)Wt2, (unsigned short*)Ab2, N);
    // final: out = dinv.*(sum Ab2) + b2  (f32)
    k_agg_f32<<<(N * 8 + 255) / 256, 256, 0, stream>>>((const uint4*)Ab2, p2, rowinfo2, nid,
                                                       cap2, M2, dinv, b2, out, N);
}